// Round 19
// baseline (438.392 us; speedup 1.0000x reference)
//
#include <hip/hip_runtime.h>
#include <cmath>

#define B_ 1024
#define CIN_ 22
#define T1_ 438
#define COUT_ 20
#define T2_ 439

// ws float offsets
#define OFF_S 0
#define OFF_M 32
#define OFF_SUM2 576
#define OFF_SSQ2 608
#define OFF_A2 640
#define OFF_ACC_END 704
#define OFF_C 1024
#define OFF_WEFF (OFF_C + B_*3*400)
#define OFF_BPRE (OFF_WEFF + 5280)

__global__ __launch_bounds__(256) void k_zero(float* ws){
  for(int i=threadIdx.x; i<OFF_ACC_END; i+=256) ws[i]=0.f;
}

// bn1 stats via second-moment matrix of x: S[22], M[22][22] (triu), float4 dots.
// R16-proven: ONE item per thread; row stride 444 (period-8 banks, <=3-way).
__global__ __launch_bounds__(256) void k_moment(const float* __restrict__ x, float* __restrict__ ws){
  __shared__ float xs[CIN_][444];
  int b=blockIdx.x, tid=threadIdx.x;
  const float* xb = x + (size_t)b*CIN_*T1_;
  for(int i=tid;i<CIN_*T1_;i+=256){
    int h=i/T1_, t=i-h*T1_;
    xs[h][t]=xb[i];
  }
  if(tid<CIN_){
    #pragma unroll
    for(int t=T1_;t<444;t++) xs[tid][t]=0.f;
  }
  __syncthreads();
  for(int tgt=tid; tgt<275; tgt+=256){
    if(tgt<253){
      int r=tgt, i=0;
      while(true){ int c=CIN_-i; if(r<c) break; r-=c; i++; }
      int j=i+r;
      const float4* ri=(const float4*)&xs[i][0];
      const float4* rj=(const float4*)&xs[j][0];
      float acc=0.f;
      for(int t=0;t<111;t++){
        float4 a=ri[t], bb=rj[t];
        acc += a.x*bb.x + a.y*bb.y + a.z*bb.z + a.w*bb.w;
      }
      atomicAdd(&ws[OFF_M + i*CIN_ + j], acc);
    } else {
      int c=tgt-253;
      const float4* rc=(const float4*)&xs[c][0];
      float acc=0.f;
      for(int t=0;t<111;t++){
        float4 a=rc[t];
        acc += a.x + a.y + a.z + a.w;
      }
      atomicAdd(&ws[OFF_S + c], acc);
    }
  }
}

// bn1 closed-form + fold conv1/bn1 into conv2: Weff[o][h][k], bias prefix pre[o][13]
__global__ __launch_bounds__(256) void k_prep(const float* __restrict__ w1, const float* __restrict__ cb1,
                                              const float* __restrict__ g1, const float* __restrict__ bb1,
                                              const float* __restrict__ w2, float* __restrict__ ws){
  __shared__ float a1s[CIN_], e1s[CIN_];
  int tid=threadIdx.x;
  if(tid<CIN_){
    int c=tid;
    const double N = (double)B_*T1_;
    double wS=0.0, wMw=0.0;
    for(int h=0;h<CIN_;h++) wS += (double)w1[c*CIN_+h]*(double)ws[OFF_S+h];
    for(int h=0;h<CIN_;h++){
      for(int h2=0;h2<CIN_;h2++){
        int i=h<h2?h:h2, j=h<h2?h2:h;
        wMw += (double)w1[c*CIN_+h]*(double)w1[c*CIN_+h2]*(double)ws[OFF_M+i*CIN_+j];
      }
    }
    double bc=cb1[c];
    double mean=wS/N+bc;
    double ex2=(wMw+2.0*bc*wS)/N+bc*bc;
    double var=ex2-mean*mean;
    double a1=(double)g1[c]/sqrt(var+1e-5);
    double d1=(double)bb1[c]-mean*a1;
    a1s[c]=(float)a1;
    e1s[c]=(float)(a1*bc+d1);
  }
  __syncthreads();
  for(int idx=tid; idx<5280; idx+=256){
    int o=idx/264, r=idx-o*264, h=r/12, k=r-h*12;
    float s=0.f;
    for(int i=0;i<CIN_;i++) s += w2[(o*CIN_+i)*12+k]*a1s[i]*w1[i*CIN_+h];
    ws[OFF_WEFF+idx]=s;
  }
  if(tid<COUT_){
    float pre=0.f;
    ws[OFF_BPRE+tid*13+0]=0.f;
    for(int k=0;k<12;k++){
      float wb=0.f;
      for(int i=0;i<CIN_;i++) wb += w2[(tid*CIN_+i)*12+k]*e1s[i];
      pre += wb;
      ws[OFF_BPRE+tid*13+k+1]=pre;
    }
  }
}

// direct conv x->h2 + per-patch covariance + bn2 sums. ONE (b,p) PER BLOCK.
// 16-WIDE CHUNKS (t0=cch*16, 64B-aligned) -> xw staged as 7 x ds_read_b128
// per channel (154 LDS instr/thread vs 528 scalar in the 13-chunk version).
// Tail reads run <=4 floats past xs row 21 into following LDS (in-allocation;
// values only feed outputs discarded by the t0+j<L guard).
__global__ __launch_bounds__(256) void k_cov(const float* __restrict__ x,
                                             float* __restrict__ ws){
  __shared__ float preL[260];
  __shared__ float xs[CIN_][168];
  __shared__ float h2w[COUT_][156];
  __shared__ float pmu[COUT_];
  int blk=blockIdx.x, tid=threadIdx.x;
  int b=blk/3, p=blk-3*b;
  const int off = (p==0)?0:((p==1)?147:293);
  const int L = (p==0)?147:146;
  for(int i=tid;i<260;i+=256) preL[i]=ws[OFF_BPRE+i];
  const float* xb = x + (size_t)b*CIN_*T1_;
  for(int idx=tid; idx<CIN_*168; idx+=256){
    int h=idx/168, c2=idx-h*168;
    int gxt = off-6+c2;
    xs[h][c2] = (c2<167 && gxt>=0 && gxt<T1_) ? xb[h*T1_+gxt] : 0.f;
  }
  __syncthreads();
  if(tid<200){
    int o = tid/10, cch = tid-10*o;
    int t0 = cch*16;
    float acc[16];
    #pragma unroll
    for(int j=0;j<16;j++){
      int gt = off+t0+j;
      int kmin = 6-gt; kmin = kmin<0?0:kmin;
      int kmax = 443-gt; kmax = kmax>11?11:kmax;
      acc[j] = (kmax>=kmin)? preL[o*13+kmax+1]-preL[o*13+kmin] : 0.f;
    }
    const float* Wo = ws + OFF_WEFF + o*264;   // global, L1-hot
    for(int h=0;h<CIN_;h++){
      float4 xv[7];
      const float4* xr = (const float4*)&xs[h][t0];
      #pragma unroll
      for(int q=0;q<7;q++) xv[q]=xr[q];
      const float* xwf = (const float*)xv;
      const float* Wh = Wo + h*12;
      #pragma unroll
      for(int k=0;k<12;k++){
        float w=Wh[k];
        #pragma unroll
        for(int j=0;j<16;j++) acc[j] += w*xwf[j+k];
      }
    }
    #pragma unroll
    for(int j=0;j<16;j++) if(t0+j<L) h2w[o][t0+j]=acc[j];
  } else {
    int npad = 156-L;
    for(int z=tid-200; z<COUT_*npad; z+=56){
      int oo=z/npad, c2=z-oo*npad;
      h2w[oo][L+c2]=0.f;
    }
  }
  __syncthreads();
  int pi=0,pj=0;
  if(tid<210){ int r=tid,i=0; while(true){int c=COUT_-i; if(r<c)break; r-=c; i++;} pi=i; pj=i+r; }
  int sc = tid-210;
  float s=0.f;
  if(tid<210){
    const float4* ri=(const float4*)&h2w[pi][0];
    const float4* rj=(const float4*)&h2w[pj][0];
    for(int t=0;t<39;t++){
      float4 a=ri[t], bb=rj[t];
      s += a.x*bb.x + a.y*bb.y + a.z*bb.z + a.w*bb.w;
    }
  } else if(sc>=0 && sc<COUT_){
    const float4* rc=(const float4*)&h2w[sc][0];
    float s1=0.f,s2=0.f;
    for(int t=0;t<39;t++){
      float4 a=rc[t];
      s1 += a.x+a.y+a.z+a.w;
      s2 += a.x*a.x+a.y*a.y+a.z*a.z+a.w*a.w;
    }
    pmu[sc]=s1/(float)L;
    atomicAdd(&ws[OFF_SUM2+sc], s1);
    atomicAdd(&ws[OFF_SSQ2+sc], s2);
  }
  __syncthreads();
  if(tid<210){
    s -= (float)L*pmu[pi]*pmu[pj];
    float* Cb = ws + OFF_C + (size_t)blk*400;
    Cb[pi*COUT_+pj]=s; Cb[pj*COUT_+pi]=s;
  }
}

// ---------------------------------------------------------------------------
// One-sided Jacobi, ONE COLUMN PER LANE (circle-method pairing, R11-verified).
// Exit 3e-2 (R17-verified: saves a sweep, absmax unchanged).
// ---------------------------------------------------------------------------
__device__ __forceinline__ void bl_jacobi18(float own[18], float &dgo,
                                            int l18, int gb, bool act, int maxsweep){
  int self = gb + l18;
  for(int sweep=0; sweep<maxsweep; sweep++){
    { float d0=0.f,d1=0.f;
      #pragma unroll
      for(int k=0;k<18;k+=2){ d0+=own[k]*own[k]; d1+=own[k+1]*own[k+1]; }
      dgo=d0+d1;
    }
    float smax=0.f;
    for(int r=0;r<17;r++){
      int t = 2*r - l18;
      t += (t<0)?17:0;
      t -= (t>=17)?17:0;
      int pa = (l18==17)? r : ((t==l18)?17:t);
      int src = act ? (gb + pa) : self;
      float oth[18];
      #pragma unroll
      for(int k=0;k<18;k++) oth[k]=__shfl(own[k], src);
      float dgx = __shfl(dgo, src);
      float a0=0.f,a1=0.f;
      #pragma unroll
      for(int k=0;k<18;k+=2){ a0+=own[k]*oth[k]; a1+=own[k+1]*oth[k+1]; }
      float apq=a0+a1;
      bool isP = l18 < pa;
      float dgp = isP? dgo : dgx;
      float dgq = isP? dgx : dgo;
      float tau = __fdividef(dgq-dgp, 2.f*apq);
      float tt  = __fdividef(copysignf(1.f,tau), fabsf(tau)+sqrtf(1.f+tau*tau));
      float c   = rsqrtf(1.f+tt*tt);
      float s   = tt*c;
      bool  z   = (apq==0.f) || !act;
      tt=z?0.f:tt; c=z?1.f:c; s=z?0.f:s;
      smax=fmaxf(smax,fabsf(s));
      float sgn = isP ? -s : s;       // p: c*p - s*q ; q: s*p + c*q
      #pragma unroll
      for(int k=0;k<18;k++) own[k] = c*own[k] + sgn*oth[k];
      dgo = isP ? (dgp - tt*apq) : (dgq + tt*apq);
    }
    if(__all(smax<3e-2f)) break;
  }
  float d0=0.f,d1=0.f;
  #pragma unroll
  for(int k=0;k<18;k+=2){ d0+=own[k]*own[k]; d1+=own[k+1]*own[k+1]; }
  dgo=d0+d1;
}

// LDS float offsets for k_fused (S[6374] = ~25.5 KB)
#define F_A2S 0
#define F_WA 20
#define F_CS 1100
#define F_TT 2300
#define F_TRS 3434
#define F_LTR 3437
#define F_LG 3440
#define F_E9 6356
#define F_PROB 6365
// aliases (dead-region reuse):
#define F_SC 20        // Mc1: per-wave w at F_SC + w*1026 (3x342 each)
#define F_GL1 3098     // 3 x 54
#define F_ML 20        // 972 (after Mc1 dead)
#define F_MC2 992      // 3 x 342
#define F_GL2 2018     // 54
#define F_FEAT 3440    // 513 (aliases lg, dead after ml)

// Fused: per block (batch b): 3 waves, wave w = patch p.
// Congruence uses COLUMN-CACHED remap: phase a caches C[:,j] (j=lane%20) in
// registers, phase b caches W[:,c] (c=lane%18) — LDS instr 1440 -> 876/wave.
__global__ __launch_bounds__(192) void k_fused(const float* __restrict__ Wq,
                                               const float* __restrict__ Wk,
                                               const float* __restrict__ Wv,
                                               const float* __restrict__ g2,
                                               const float* __restrict__ lw,
                                               const float* __restrict__ lb,
                                               float* __restrict__ ws,
                                               float* __restrict__ out){
  __shared__ float S[6374];
  int b=blockIdx.x, tid=threadIdx.x;
  int w=tid>>6, wl=tid&63;
  if(tid<20){
    const double N=(double)B_*T2_;
    double m=(double)ws[OFF_SUM2+tid]/N;
    double v=(double)ws[OFF_SSQ2+tid]/N - m*m;
    S[F_A2S+tid]=(float)((double)g2[tid]/sqrt(v+1e-5));
  }
  __syncthreads();
  // Wa = W * a2 (block-wide)
  for(int i=tid;i<1080;i+=192){
    int m=i/360, r=i-m*360, row=r/18;
    const float* W=(m==0)?Wq:((m==1)?Wk:Wv);
    S[F_WA+i]=W[r]*S[F_A2S+row];
  }
  // per-wave: stage this patch's C
  {
    const float* Cb=ws+OFF_C+((size_t)b*3+w)*400;
    for(int i=wl;i<400;i+=64) S[F_CS+w*400+i]=Cb[i];
  }
  // trace (lane 0 of each wave; in-wave DS order guarantees Cs visible)
  if(wl==0){
    float tr=0.f;
    #pragma unroll
    for(int i=0;i<20;i++) tr += S[F_CS+w*400+i*20+i]*S[F_A2S+i]*S[F_A2S+i];
    S[F_TRS+w]=tr;
    S[F_LTR+w]=logf(tr);
  }
  __syncthreads();
  // 3 congruences per wave: B_m = Wa_m^T C_w Wa_m -> lg[m][w]
  // phase a: lane j=wl%20 fixed -> cache C[:,j]; outputs a = wl/20 + 3s
  {
    const float* Cw=S+F_CS+w*400;
    float creg[20];
    int j = wl%20, ab = wl/20;   // ab in 0..2 for wl<60
    if(wl<60){
      #pragma unroll
      for(int i=0;i<20;i++) creg[i]=Cw[i*20+j];
    }
    for(int m=0;m<3;m++){
      const float* Wm=S+F_WA+m*360;
      float* Tw=S+F_TT+w*378;
      if(wl<60){
        #pragma unroll
        for(int s6=0;s6<6;s6++){
          int a = ab + 3*s6;
          float t=0.f;
          #pragma unroll
          for(int i=0;i<20;i++) t += Wm[i*18+a]*creg[i];
          Tw[a*21+j]=t;
        }
      }
      __syncthreads();
      // phase b: lane c=wl%18 fixed -> cache Wm[:,c]; outputs a = wl/18 + 3s
      {
        int c = wl%18, ab2 = wl/18;   // ab2 in 0..2 for wl<54
        if(wl<54){
          float wreg[20];
          #pragma unroll
          for(int jj=0;jj<20;jj++) wreg[jj]=Wm[jj*18+c];
          #pragma unroll
          for(int s6=0;s6<6;s6++){
            int a = ab2 + 3*s6;
            float t=0.f;
            #pragma unroll
            for(int jj=0;jj<20;jj++) t += Tw[a*21+jj]*wreg[jj];
            S[F_LG + m*972 + w*324 + a*18 + c]=t;
          }
        }
      }
      __syncthreads();
    }
  }
  int g=wl/18, l18=wl-18*g;
  bool act=(g<3);
  float tr_w=S[F_TRS+w], ltr_w=S[F_LTR+w];
  float sh=1e-5f*tr_w;
  float own[18], dgo=0.f;
  if(act){
    const float* Ag=S+F_LG+g*972+w*324;
    #pragma unroll
    for(int k=0;k<18;k++)
      own[k]=0.5f*(Ag[k*18+l18]+Ag[l18*18+k]) + ((k==l18)?sh:0.f);
  } else {
    #pragma unroll
    for(int k=0;k<18;k++) own[k]=0.f;
  }
  __syncthreads();   // all reads of Wa/Cs/Tt/lg-B done; Mc1 may alias
  bl_jacobi18(own,dgo,l18,g*18,act,8);
  // spectral weight: lambda_true=sqrt(dg)/tr; gv=(0.5*log(dg)-log(tr))/dg
  float dp=fmaxf(dgo,1e-30f);
  float gv=__fdividef(0.5f*logf(dp)-ltr_w, dp);
  float* Mc1=S+F_SC+w*1026;
  float* gl1=S+F_GL1+w*54;
  if(act){
    #pragma unroll
    for(int k=0;k<18;k++) Mc1[g*342 + k*19 + l18]=own[k];
    gl1[g*18+l18]=gv;
  }
  // logm rows -> lg[mat][w] (in-wave: DS in-order after Mc1 writes)
  if(wl<54){
    int mat=g, i=l18;
    float w18[18];
    #pragma unroll
    for(int k=0;k<18;k++) w18[k]=gl1[mat*18+k]*Mc1[mat*342+i*19+k];
    float* ob=S+F_LG+mat*972+w*324+i*18;
    for(int j=0;j<18;j++){
      float s=0.f;
      #pragma unroll
      for(int k=0;k<18;k++) s += w18[k]*Mc1[mat*342+j*19+k];
      ob[j]=s;
    }
  }
  __syncthreads();   // lg (logQ|logK|logV) complete
  // energies (wave 0, 36 lanes: 9 dots x 4-lane split)
  if(tid<36){
    int d=tid>>2, sub=tid&3;
    int ii=d/3, p=d-ii*3;
    const float* kk=S+F_LG+972+ii*324+sub*81;
    const float* qq=S+F_LG+p*324+sub*81;
    float s=0.f;
    for(int el=0;el<81;el++){ float dd=kk[el]-qq[el]; s+=dd*dd; }
    s += __shfl_xor(s,1); s += __shfl_xor(s,2);
    if(sub==0) S[F_E9+d]=s;
  }
  __syncthreads();
  if(tid<3){
    int p=tid;
    float f0=1.f/(1.f+log1pf(S[F_E9+0+p]));
    float f1=1.f/(1.f+log1pf(S[F_E9+3+p]));
    float f2=1.f/(1.f+log1pf(S[F_E9+6+p]));
    float mx=fmaxf(f0,fmaxf(f1,f2));
    float x0=expf(f0-mx), x1=expf(f1-mx), x2=expf(f2-mx);
    float inv=1.f/(x0+x1+x2);
    S[F_PROB+p*3+0]=x0*inv; S[F_PROB+p*3+1]=x1*inv; S[F_PROB+p*3+2]=x2*inv;
  }
  __syncthreads();
  // ml = sum_i prob * logV  (Mc1 dead -> F_ML aliases it)
  for(int idx=tid; idx<972; idx+=192){
    int p=idx/324, el=idx-p*324;
    const float* LV=S+F_LG+1944;
    S[F_ML+idx]=S[F_PROB+p*3+0]*LV[el]+S[F_PROB+p*3+1]*LV[324+el]+S[F_PROB+p*3+2]*LV[648+el];
  }
  __syncthreads();
  // eigh2: WAVE 0 ONLY — 54 lanes handle all 3 ml matrices (+12I shift).
  if(w==0){
    int g2i=wl/18, l2=wl-18*g2i;
    bool act2=(g2i<3);
    float own2[18], dgo2=0.f;
    if(act2){
      const float* Ag=S+F_ML+g2i*324;
      #pragma unroll
      for(int k=0;k<18;k++)
        own2[k]=0.5f*(Ag[k*18+l2]+Ag[l2*18+k]) + ((k==l2)?12.f:0.f);
    } else {
      #pragma unroll
      for(int k=0;k<18;k++) own2[k]=0.f;
    }
    bl_jacobi18(own2,dgo2,l2,g2i*18,act2,8);
    float lam=sqrtf(fmaxf(dgo2,1e-12f));
    float gv2=__fdividef(fmaxf(lam-12.f,-9.2103404f), fmaxf(dgo2,1e-12f));
    if(act2){
      #pragma unroll
      for(int k=0;k<18;k++) S[F_MC2 + g2i*342 + k*19 + l2]=own2[k];
      S[F_GL2 + g2i*18 + l2]=gv2;
    }
  }
  __syncthreads();   // all Mc2/gl2 ready
  // triu(tang) -> feat (aliases lg region, dead)
  if(tid<54){
    int mat=tid/18, i=tid-mat*18;
    float w18[18];
    #pragma unroll
    for(int k=0;k<18;k++) w18[k]=S[F_GL2+mat*18+k]*S[F_MC2+mat*342+i*19+k];
    int base = mat*171 + (i*18 - (i*(i-1))/2) - i;
    for(int j=i;j<18;j++){
      float s=0.f;
      #pragma unroll
      for(int k=0;k<18;k++) s += w18[k]*S[F_MC2+mat*342+j*19+k];
      S[F_FEAT+base+j]=s;
    }
  }
  __syncthreads();
  // linear (wave 0): out[b][j] = lb[j] + dot(feat, lw[j])
  if(tid<64){
    int j4 = tid&3, chunk = tid>>2;
    float s=0.f;
    const float* wj = lw + j4*513;
    for(int k=chunk; k<513; k+=16) s += S[F_FEAT+k]*wj[k];
    s += __shfl_xor(s,4); s += __shfl_xor(s,8);
    s += __shfl_xor(s,16); s += __shfl_xor(s,32);
    if(chunk==0) out[b*4+j4] = s + lb[j4];
  }
}

extern "C" void kernel_launch(void* const* d_in, const int* in_sizes, int n_in,
                              void* d_out, int out_size, void* d_ws, size_t ws_size,
                              hipStream_t stream){
  const float* x  =(const float*)d_in[0];
  const float* w1 =(const float*)d_in[1];
  const float* cb1=(const float*)d_in[2];
  const float* g1 =(const float*)d_in[3];
  const float* bb1=(const float*)d_in[4];
  const float* w2 =(const float*)d_in[5];
  // d_in[6] conv2_b, d_in[8] bn2_b: provably cancel
  const float* g2 =(const float*)d_in[7];
  const float* Wq =(const float*)d_in[9];
  const float* Wk =(const float*)d_in[10];
  const float* Wv =(const float*)d_in[11];
  const float* lw =(const float*)d_in[12];
  const float* lb =(const float*)d_in[13];
  float* ws=(float*)d_ws;
  float* out=(float*)d_out;

  k_zero<<<1,256,0,stream>>>(ws);
  k_moment<<<B_,256,0,stream>>>(x,ws);
  k_prep<<<1,256,0,stream>>>(w1,cb1,g1,bb1,w2,ws);
  k_cov<<<3072,256,0,stream>>>(x,ws);            // one (b,p) per block
  k_fused<<<B_,192,0,stream>>>(Wq,Wk,Wv,g2,lw,lb,ws,out);  // fin2+eigh3+att+eigh2+feat+linear
}

// Round 20
// 377.206 us; speedup vs baseline: 1.1622x; 1.1622x over previous
//
#include <hip/hip_runtime.h>
#include <cmath>

#define B_ 1024
#define CIN_ 22
#define T1_ 438
#define COUT_ 20
#define T2_ 439

// ws float offsets
#define OFF_S 0
#define OFF_M 32
#define OFF_SUM2 576
#define OFF_SSQ2 608
#define OFF_A2 640
#define OFF_ACC_END 704
#define OFF_C 1024
#define OFF_WEFF (OFF_C + B_*3*400)
#define OFF_BPRE (OFF_WEFF + 5280)

__global__ __launch_bounds__(256) void k_zero(float* ws){
  for(int i=threadIdx.x; i<OFF_ACC_END; i+=256) ws[i]=0.f;
}

// bn1 stats via second-moment matrix of x: S[22], M[22][22] (triu), float4 dots.
// R16-proven: ONE item per thread; row stride 444 (period-8 banks, <=3-way).
__global__ __launch_bounds__(256) void k_moment(const float* __restrict__ x, float* __restrict__ ws){
  __shared__ float xs[CIN_][444];
  int b=blockIdx.x, tid=threadIdx.x;
  const float* xb = x + (size_t)b*CIN_*T1_;
  for(int i=tid;i<CIN_*T1_;i+=256){
    int h=i/T1_, t=i-h*T1_;
    xs[h][t]=xb[i];
  }
  if(tid<CIN_){
    #pragma unroll
    for(int t=T1_;t<444;t++) xs[tid][t]=0.f;
  }
  __syncthreads();
  for(int tgt=tid; tgt<275; tgt+=256){
    if(tgt<253){
      int r=tgt, i=0;
      while(true){ int c=CIN_-i; if(r<c) break; r-=c; i++; }
      int j=i+r;
      const float4* ri=(const float4*)&xs[i][0];
      const float4* rj=(const float4*)&xs[j][0];
      float acc=0.f;
      for(int t=0;t<111;t++){
        float4 a=ri[t], bb=rj[t];
        acc += a.x*bb.x + a.y*bb.y + a.z*bb.z + a.w*bb.w;
      }
      atomicAdd(&ws[OFF_M + i*CIN_ + j], acc);
    } else {
      int c=tgt-253;
      const float4* rc=(const float4*)&xs[c][0];
      float acc=0.f;
      for(int t=0;t<111;t++){
        float4 a=rc[t];
        acc += a.x + a.y + a.z + a.w;
      }
      atomicAdd(&ws[OFF_S + c], acc);
    }
  }
}

// bn1 closed-form + fold conv1/bn1 into conv2: Weff[o][h][k], bias prefix pre[o][13]
__global__ __launch_bounds__(256) void k_prep(const float* __restrict__ w1, const float* __restrict__ cb1,
                                              const float* __restrict__ g1, const float* __restrict__ bb1,
                                              const float* __restrict__ w2, float* __restrict__ ws){
  __shared__ float a1s[CIN_], e1s[CIN_];
  int tid=threadIdx.x;
  if(tid<CIN_){
    int c=tid;
    const double N = (double)B_*T1_;
    double wS=0.0, wMw=0.0;
    for(int h=0;h<CIN_;h++) wS += (double)w1[c*CIN_+h]*(double)ws[OFF_S+h];
    for(int h=0;h<CIN_;h++){
      for(int h2=0;h2<CIN_;h2++){
        int i=h<h2?h:h2, j=h<h2?h2:h;
        wMw += (double)w1[c*CIN_+h]*(double)w1[c*CIN_+h2]*(double)ws[OFF_M+i*CIN_+j];
      }
    }
    double bc=cb1[c];
    double mean=wS/N+bc;
    double ex2=(wMw+2.0*bc*wS)/N+bc*bc;
    double var=ex2-mean*mean;
    double a1=(double)g1[c]/sqrt(var+1e-5);
    double d1=(double)bb1[c]-mean*a1;
    a1s[c]=(float)a1;
    e1s[c]=(float)(a1*bc+d1);
  }
  __syncthreads();
  for(int idx=tid; idx<5280; idx+=256){
    int o=idx/264, r=idx-o*264, h=r/12, k=r-h*12;
    float s=0.f;
    for(int i=0;i<CIN_;i++) s += w2[(o*CIN_+i)*12+k]*a1s[i]*w1[i*CIN_+h];
    ws[OFF_WEFF+idx]=s;
  }
  if(tid<COUT_){
    float pre=0.f;
    ws[OFF_BPRE+tid*13+0]=0.f;
    for(int k=0;k<12;k++){
      float wb=0.f;
      for(int i=0;i<CIN_;i++) wb += w2[(tid*CIN_+i)*12+k]*e1s[i];
      pre += wb;
      ws[OFF_BPRE+tid*13+k+1]=pre;
    }
  }
}

// direct conv x->h2 + per-patch covariance + bn2 sums. ONE (b,p) PER BLOCK.
// R18-proven 13-chunk / 240-thread version (R19's 16-chunk regressed:
// longer per-thread serial path + fewer lanes beat the b128 win — rule x4).
__global__ __launch_bounds__(256) void k_cov(const float* __restrict__ x,
                                             float* __restrict__ ws){
  __shared__ float preL[260];
  __shared__ float xs[CIN_][168];
  __shared__ float h2w[COUT_][156];
  __shared__ float pmu[COUT_];
  int blk=blockIdx.x, tid=threadIdx.x;
  int b=blk/3, p=blk-3*b;
  const int off = (p==0)?0:((p==1)?147:293);
  const int L = (p==0)?147:146;
  for(int i=tid;i<260;i+=256) preL[i]=ws[OFF_BPRE+i];
  const float* xb = x + (size_t)b*CIN_*T1_;
  for(int idx=tid; idx<CIN_*168; idx+=256){
    int h=idx/168, c2=idx-h*168;
    int gxt = off-6+c2;
    xs[h][c2] = (c2<167 && gxt>=0 && gxt<T1_) ? xb[h*T1_+gxt] : 0.f;
  }
  __syncthreads();
  int o = tid/12, cch = tid-12*o;
  int t0 = cch*13;
  if(tid<240){
    float acc[13];
    #pragma unroll
    for(int j=0;j<13;j++){
      int gt = off+t0+j;
      int kmin = 6-gt; kmin = kmin<0?0:kmin;
      int kmax = 443-gt; kmax = kmax>11?11:kmax;
      acc[j] = (kmax>=kmin)? preL[o*13+kmax+1]-preL[o*13+kmin] : 0.f;
    }
    const float* Wo = ws + OFF_WEFF + o*264;   // global, L1-hot
    for(int h=0;h<CIN_;h++){
      float xw[24];
      #pragma unroll
      for(int c2=0;c2<24;c2++) xw[c2]=xs[h][t0+c2];
      const float* Wh = Wo + h*12;
      #pragma unroll
      for(int k=0;k<12;k++){
        float w=Wh[k];
        #pragma unroll
        for(int j=0;j<13;j++) acc[j] += w*xw[j+k];
      }
    }
    #pragma unroll
    for(int j=0;j<13;j++) if(t0+j<L) h2w[o][t0+j]=acc[j];
  } else {
    int npad = 156-L;
    for(int z=tid-240; z<COUT_*npad; z+=16){
      int oo=z/npad, c2=z-oo*npad;
      h2w[oo][L+c2]=0.f;
    }
  }
  __syncthreads();
  int pi=0,pj=0;
  if(tid<210){ int r=tid,i=0; while(true){int c=COUT_-i; if(r<c)break; r-=c; i++;} pi=i; pj=i+r; }
  int sc = tid-210;
  float s=0.f;
  if(tid<210){
    const float4* ri=(const float4*)&h2w[pi][0];
    const float4* rj=(const float4*)&h2w[pj][0];
    for(int t=0;t<39;t++){
      float4 a=ri[t], bb=rj[t];
      s += a.x*bb.x + a.y*bb.y + a.z*bb.z + a.w*bb.w;
    }
  } else if(sc>=0 && sc<COUT_){
    const float4* rc=(const float4*)&h2w[sc][0];
    float s1=0.f,s2=0.f;
    for(int t=0;t<39;t++){
      float4 a=rc[t];
      s1 += a.x+a.y+a.z+a.w;
      s2 += a.x*a.x+a.y*a.y+a.z*a.z+a.w*a.w;
    }
    pmu[sc]=s1/(float)L;
    atomicAdd(&ws[OFF_SUM2+sc], s1);
    atomicAdd(&ws[OFF_SSQ2+sc], s2);
  }
  __syncthreads();
  if(tid<210){
    s -= (float)L*pmu[pi]*pmu[pj];
    float* Cb = ws + OFF_C + (size_t)blk*400;
    Cb[pi*COUT_+pj]=s; Cb[pj*COUT_+pi]=s;
  }
}

// ---------------------------------------------------------------------------
// One-sided Jacobi, ONE COLUMN PER LANE (circle-method pairing, R11-verified).
// Exit 3e-2 (R17-verified: saves a sweep, absmax unchanged).
// ---------------------------------------------------------------------------
__device__ __forceinline__ void bl_jacobi18(float own[18], float &dgo,
                                            int l18, int gb, bool act, int maxsweep){
  int self = gb + l18;
  for(int sweep=0; sweep<maxsweep; sweep++){
    { float d0=0.f,d1=0.f;
      #pragma unroll
      for(int k=0;k<18;k+=2){ d0+=own[k]*own[k]; d1+=own[k+1]*own[k+1]; }
      dgo=d0+d1;
    }
    float smax=0.f;
    for(int r=0;r<17;r++){
      int t = 2*r - l18;
      t += (t<0)?17:0;
      t -= (t>=17)?17:0;
      int pa = (l18==17)? r : ((t==l18)?17:t);
      int src = act ? (gb + pa) : self;
      float oth[18];
      #pragma unroll
      for(int k=0;k<18;k++) oth[k]=__shfl(own[k], src);
      float dgx = __shfl(dgo, src);
      float a0=0.f,a1=0.f;
      #pragma unroll
      for(int k=0;k<18;k+=2){ a0+=own[k]*oth[k]; a1+=own[k+1]*oth[k+1]; }
      float apq=a0+a1;
      bool isP = l18 < pa;
      float dgp = isP? dgo : dgx;
      float dgq = isP? dgx : dgo;
      float tau = __fdividef(dgq-dgp, 2.f*apq);
      float tt  = __fdividef(copysignf(1.f,tau), fabsf(tau)+sqrtf(1.f+tau*tau));
      float c   = rsqrtf(1.f+tt*tt);
      float s   = tt*c;
      bool  z   = (apq==0.f) || !act;
      tt=z?0.f:tt; c=z?1.f:c; s=z?0.f:s;
      smax=fmaxf(smax,fabsf(s));
      float sgn = isP ? -s : s;       // p: c*p - s*q ; q: s*p + c*q
      #pragma unroll
      for(int k=0;k<18;k++) own[k] = c*own[k] + sgn*oth[k];
      dgo = isP ? (dgp - tt*apq) : (dgq + tt*apq);
    }
    if(__all(smax<3e-2f)) break;
  }
  float d0=0.f,d1=0.f;
  #pragma unroll
  for(int k=0;k<18;k+=2){ d0+=own[k]*own[k]; d1+=own[k+1]*own[k+1]; }
  dgo=d0+d1;
}

// LDS float offsets for k_fused (S[6374] = ~25.5 KB)
#define F_A2S 0
#define F_WA 20
#define F_CS 1100
#define F_TT 2300
#define F_TRS 3434
#define F_LTR 3437
#define F_LG 3440
#define F_E9 6356
#define F_PROB 6365
// aliases (dead-region reuse):
#define F_SC 20        // Mc1: per-wave w at F_SC + w*1026 (3x342 each)
#define F_GL1 3098     // 3 x 54
#define F_ML 20        // 972 (after Mc1 dead)
#define F_MC2 992      // 3 x 342
#define F_GL2 2018     // 54
#define F_FEAT 3440    // 513 (aliases lg, dead after ml)

// Fused: per block (batch b): 3 waves, wave w = patch p.
// Congruence uses COLUMN-CACHED remap (R19-verified, -6us): phase a caches
// C[:,j] in regs, phase b caches W[:,c].
__global__ __launch_bounds__(192) void k_fused(const float* __restrict__ Wq,
                                               const float* __restrict__ Wk,
                                               const float* __restrict__ Wv,
                                               const float* __restrict__ g2,
                                               const float* __restrict__ lw,
                                               const float* __restrict__ lb,
                                               float* __restrict__ ws,
                                               float* __restrict__ out){
  __shared__ float S[6374];
  int b=blockIdx.x, tid=threadIdx.x;
  int w=tid>>6, wl=tid&63;
  if(tid<20){
    const double N=(double)B_*T2_;
    double m=(double)ws[OFF_SUM2+tid]/N;
    double v=(double)ws[OFF_SSQ2+tid]/N - m*m;
    S[F_A2S+tid]=(float)((double)g2[tid]/sqrt(v+1e-5));
  }
  __syncthreads();
  // Wa = W * a2 (block-wide)
  for(int i=tid;i<1080;i+=192){
    int m=i/360, r=i-m*360, row=r/18;
    const float* W=(m==0)?Wq:((m==1)?Wk:Wv);
    S[F_WA+i]=W[r]*S[F_A2S+row];
  }
  // per-wave: stage this patch's C
  {
    const float* Cb=ws+OFF_C+((size_t)b*3+w)*400;
    for(int i=wl;i<400;i+=64) S[F_CS+w*400+i]=Cb[i];
  }
  // trace (lane 0 of each wave; in-wave DS order guarantees Cs visible)
  if(wl==0){
    float tr=0.f;
    #pragma unroll
    for(int i=0;i<20;i++) tr += S[F_CS+w*400+i*20+i]*S[F_A2S+i]*S[F_A2S+i];
    S[F_TRS+w]=tr;
    S[F_LTR+w]=logf(tr);
  }
  __syncthreads();
  // 3 congruences per wave: B_m = Wa_m^T C_w Wa_m -> lg[m][w]
  // phase a: lane j=wl%20 fixed -> cache C[:,j]; outputs a = wl/20 + 3s
  {
    const float* Cw=S+F_CS+w*400;
    float creg[20];
    int j = wl%20, ab = wl/20;   // ab in 0..2 for wl<60
    if(wl<60){
      #pragma unroll
      for(int i=0;i<20;i++) creg[i]=Cw[i*20+j];
    }
    for(int m=0;m<3;m++){
      const float* Wm=S+F_WA+m*360;
      float* Tw=S+F_TT+w*378;
      if(wl<60){
        #pragma unroll
        for(int s6=0;s6<6;s6++){
          int a = ab + 3*s6;
          float t=0.f;
          #pragma unroll
          for(int i=0;i<20;i++) t += Wm[i*18+a]*creg[i];
          Tw[a*21+j]=t;
        }
      }
      __syncthreads();
      // phase b: lane c=wl%18 fixed -> cache Wm[:,c]; outputs a = wl/18 + 3s
      {
        int c = wl%18, ab2 = wl/18;   // ab2 in 0..2 for wl<54
        if(wl<54){
          float wreg[20];
          #pragma unroll
          for(int jj=0;jj<20;jj++) wreg[jj]=Wm[jj*18+c];
          #pragma unroll
          for(int s6=0;s6<6;s6++){
            int a = ab2 + 3*s6;
            float t=0.f;
            #pragma unroll
            for(int jj=0;jj<20;jj++) t += Tw[a*21+jj]*wreg[jj];
            S[F_LG + m*972 + w*324 + a*18 + c]=t;
          }
        }
      }
      __syncthreads();
    }
  }
  int g=wl/18, l18=wl-18*g;
  bool act=(g<3);
  float tr_w=S[F_TRS+w], ltr_w=S[F_LTR+w];
  float sh=1e-5f*tr_w;
  float own[18], dgo=0.f;
  if(act){
    const float* Ag=S+F_LG+g*972+w*324;
    #pragma unroll
    for(int k=0;k<18;k++)
      own[k]=0.5f*(Ag[k*18+l18]+Ag[l18*18+k]) + ((k==l18)?sh:0.f);
  } else {
    #pragma unroll
    for(int k=0;k<18;k++) own[k]=0.f;
  }
  __syncthreads();   // all reads of Wa/Cs/Tt/lg-B done; Mc1 may alias
  bl_jacobi18(own,dgo,l18,g*18,act,8);
  // spectral weight: lambda_true=sqrt(dg)/tr; gv=(0.5*log(dg)-log(tr))/dg
  float dp=fmaxf(dgo,1e-30f);
  float gv=__fdividef(0.5f*logf(dp)-ltr_w, dp);
  float* Mc1=S+F_SC+w*1026;
  float* gl1=S+F_GL1+w*54;
  if(act){
    #pragma unroll
    for(int k=0;k<18;k++) Mc1[g*342 + k*19 + l18]=own[k];
    gl1[g*18+l18]=gv;
  }
  // logm rows -> lg[mat][w] (in-wave: DS in-order after Mc1 writes)
  if(wl<54){
    int mat=g, i=l18;
    float w18[18];
    #pragma unroll
    for(int k=0;k<18;k++) w18[k]=gl1[mat*18+k]*Mc1[mat*342+i*19+k];
    float* ob=S+F_LG+mat*972+w*324+i*18;
    for(int j=0;j<18;j++){
      float s=0.f;
      #pragma unroll
      for(int k=0;k<18;k++) s += w18[k]*Mc1[mat*342+j*19+k];
      ob[j]=s;
    }
  }
  __syncthreads();   // lg (logQ|logK|logV) complete
  // energies (wave 0, 36 lanes: 9 dots x 4-lane split)
  if(tid<36){
    int d=tid>>2, sub=tid&3;
    int ii=d/3, p=d-ii*3;
    const float* kk=S+F_LG+972+ii*324+sub*81;
    const float* qq=S+F_LG+p*324+sub*81;
    float s=0.f;
    for(int el=0;el<81;el++){ float dd=kk[el]-qq[el]; s+=dd*dd; }
    s += __shfl_xor(s,1); s += __shfl_xor(s,2);
    if(sub==0) S[F_E9+d]=s;
  }
  __syncthreads();
  if(tid<3){
    int p=tid;
    float f0=1.f/(1.f+log1pf(S[F_E9+0+p]));
    float f1=1.f/(1.f+log1pf(S[F_E9+3+p]));
    float f2=1.f/(1.f+log1pf(S[F_E9+6+p]));
    float mx=fmaxf(f0,fmaxf(f1,f2));
    float x0=expf(f0-mx), x1=expf(f1-mx), x2=expf(f2-mx);
    float inv=1.f/(x0+x1+x2);
    S[F_PROB+p*3+0]=x0*inv; S[F_PROB+p*3+1]=x1*inv; S[F_PROB+p*3+2]=x2*inv;
  }
  __syncthreads();
  // ml = sum_i prob * logV  (Mc1 dead -> F_ML aliases it)
  for(int idx=tid; idx<972; idx+=192){
    int p=idx/324, el=idx-p*324;
    const float* LV=S+F_LG+1944;
    S[F_ML+idx]=S[F_PROB+p*3+0]*LV[el]+S[F_PROB+p*3+1]*LV[324+el]+S[F_PROB+p*3+2]*LV[648+el];
  }
  __syncthreads();
  // eigh2: WAVE 0 ONLY — 54 lanes handle all 3 ml matrices (+12I shift).
  if(w==0){
    int g2i=wl/18, l2=wl-18*g2i;
    bool act2=(g2i<3);
    float own2[18], dgo2=0.f;
    if(act2){
      const float* Ag=S+F_ML+g2i*324;
      #pragma unroll
      for(int k=0;k<18;k++)
        own2[k]=0.5f*(Ag[k*18+l2]+Ag[l2*18+k]) + ((k==l2)?12.f:0.f);
    } else {
      #pragma unroll
      for(int k=0;k<18;k++) own2[k]=0.f;
    }
    bl_jacobi18(own2,dgo2,l2,g2i*18,act2,8);
    float lam=sqrtf(fmaxf(dgo2,1e-12f));
    float gv2=__fdividef(fmaxf(lam-12.f,-9.2103404f), fmaxf(dgo2,1e-12f));
    if(act2){
      #pragma unroll
      for(int k=0;k<18;k++) S[F_MC2 + g2i*342 + k*19 + l2]=own2[k];
      S[F_GL2 + g2i*18 + l2]=gv2;
    }
  }
  __syncthreads();   // all Mc2/gl2 ready
  // triu(tang) -> feat (aliases lg region, dead)
  if(tid<54){
    int mat=tid/18, i=tid-mat*18;
    float w18[18];
    #pragma unroll
    for(int k=0;k<18;k++) w18[k]=S[F_GL2+mat*18+k]*S[F_MC2+mat*342+i*19+k];
    int base = mat*171 + (i*18 - (i*(i-1))/2) - i;
    for(int j=i;j<18;j++){
      float s=0.f;
      #pragma unroll
      for(int k=0;k<18;k++) s += w18[k]*S[F_MC2+mat*342+j*19+k];
      S[F_FEAT+base+j]=s;
    }
  }
  __syncthreads();
  // linear (wave 0): out[b][j] = lb[j] + dot(feat, lw[j])
  if(tid<64){
    int j4 = tid&3, chunk = tid>>2;
    float s=0.f;
    const float* wj = lw + j4*513;
    for(int k=chunk; k<513; k+=16) s += S[F_FEAT+k]*wj[k];
    s += __shfl_xor(s,4); s += __shfl_xor(s,8);
    s += __shfl_xor(s,16); s += __shfl_xor(s,32);
    if(chunk==0) out[b*4+j4] = s + lb[j4];
  }
}

extern "C" void kernel_launch(void* const* d_in, const int* in_sizes, int n_in,
                              void* d_out, int out_size, void* d_ws, size_t ws_size,
                              hipStream_t stream){
  const float* x  =(const float*)d_in[0];
  const float* w1 =(const float*)d_in[1];
  const float* cb1=(const float*)d_in[2];
  const float* g1 =(const float*)d_in[3];
  const float* bb1=(const float*)d_in[4];
  const float* w2 =(const float*)d_in[5];
  // d_in[6] conv2_b, d_in[8] bn2_b: provably cancel
  const float* g2 =(const float*)d_in[7];
  const float* Wq =(const float*)d_in[9];
  const float* Wk =(const float*)d_in[10];
  const float* Wv =(const float*)d_in[11];
  const float* lw =(const float*)d_in[12];
  const float* lb =(const float*)d_in[13];
  float* ws=(float*)d_ws;
  float* out=(float*)d_out;

  k_zero<<<1,256,0,stream>>>(ws);
  k_moment<<<B_,256,0,stream>>>(x,ws);
  k_prep<<<1,256,0,stream>>>(w1,cb1,g1,bb1,w2,ws);
  k_cov<<<3072,256,0,stream>>>(x,ws);            // one (b,p) per block
  k_fused<<<B_,192,0,stream>>>(Wq,Wk,Wv,g2,lw,lb,ws,out);  // fin2+eigh3+att+eigh2+feat+linear
}

// Round 21
// 376.879 us; speedup vs baseline: 1.1632x; 1.0009x over previous
//
#include <hip/hip_runtime.h>
#include <cmath>

#define B_ 1024
#define CIN_ 22
#define T1_ 438
#define COUT_ 20
#define T2_ 439

// ws float offsets
#define OFF_S 0
#define OFF_M 32
#define OFF_SUM2 576
#define OFF_SSQ2 608
#define OFF_A2 640
#define OFF_ACC_END 704
#define OFF_C 1024
#define OFF_WEFF (OFF_C + B_*3*400)
#define OFF_BPRE (OFF_WEFF + 5280)

__global__ __launch_bounds__(256) void k_zero(float* ws){
  for(int i=threadIdx.x; i<OFF_ACC_END; i+=256) ws[i]=0.f;
}

// bn1 stats via second-moment matrix of x: S[22], M[22][22] (triu), float4 dots.
// GLOBAL LOADS VECTORIZED (float4, 2409 per block): the scalar-load version
// was HBM-latency-bound at ~66 GB/s (4KB in flight/CU vs ~900cyc latency).
// Batch block is 9636 floats (16B-aligned, %4==0). LDS scatter stays scalar
// (straddles row boundaries); row stride 444 (period-8 banks, <=3-way).
__global__ __launch_bounds__(256) void k_moment(const float* __restrict__ x, float* __restrict__ ws){
  __shared__ float xs[CIN_][444];
  int b=blockIdx.x, tid=threadIdx.x;
  const float* xb = x + (size_t)b*CIN_*T1_;
  const float4* xb4 = (const float4*)xb;
  for(int i4=tid; i4<2409; i4+=256){
    float4 v = xb4[i4];
    int e = i4<<2;
    int h0=e/T1_,     t0=e-h0*T1_;
    int h1=(e+1)/T1_, t1=(e+1)-h1*T1_;
    int h2=(e+2)/T1_, t2=(e+2)-h2*T1_;
    int h3=(e+3)/T1_, t3=(e+3)-h3*T1_;
    xs[h0][t0]=v.x; xs[h1][t1]=v.y; xs[h2][t2]=v.z; xs[h3][t3]=v.w;
  }
  if(tid<CIN_){
    #pragma unroll
    for(int t=T1_;t<444;t++) xs[tid][t]=0.f;
  }
  __syncthreads();
  for(int tgt=tid; tgt<275; tgt+=256){
    if(tgt<253){
      int r=tgt, i=0;
      while(true){ int c=CIN_-i; if(r<c) break; r-=c; i++; }
      int j=i+r;
      const float4* ri=(const float4*)&xs[i][0];
      const float4* rj=(const float4*)&xs[j][0];
      float acc=0.f;
      for(int t=0;t<111;t++){
        float4 a=ri[t], bb=rj[t];
        acc += a.x*bb.x + a.y*bb.y + a.z*bb.z + a.w*bb.w;
      }
      atomicAdd(&ws[OFF_M + i*CIN_ + j], acc);
    } else {
      int c=tgt-253;
      const float4* rc=(const float4*)&xs[c][0];
      float acc=0.f;
      for(int t=0;t<111;t++){
        float4 a=rc[t];
        acc += a.x + a.y + a.z + a.w;
      }
      atomicAdd(&ws[OFF_S + c], acc);
    }
  }
}

// bn1 closed-form + fold conv1/bn1 into conv2: Weff[o][h][k], bias prefix pre[o][13]
__global__ __launch_bounds__(256) void k_prep(const float* __restrict__ w1, const float* __restrict__ cb1,
                                              const float* __restrict__ g1, const float* __restrict__ bb1,
                                              const float* __restrict__ w2, float* __restrict__ ws){
  __shared__ float a1s[CIN_], e1s[CIN_];
  int tid=threadIdx.x;
  if(tid<CIN_){
    int c=tid;
    const double N = (double)B_*T1_;
    double wS=0.0, wMw=0.0;
    for(int h=0;h<CIN_;h++) wS += (double)w1[c*CIN_+h]*(double)ws[OFF_S+h];
    for(int h=0;h<CIN_;h++){
      for(int h2=0;h2<CIN_;h2++){
        int i=h<h2?h:h2, j=h<h2?h2:h;
        wMw += (double)w1[c*CIN_+h]*(double)w1[c*CIN_+h2]*(double)ws[OFF_M+i*CIN_+j];
      }
    }
    double bc=cb1[c];
    double mean=wS/N+bc;
    double ex2=(wMw+2.0*bc*wS)/N+bc*bc;
    double var=ex2-mean*mean;
    double a1=(double)g1[c]/sqrt(var+1e-5);
    double d1=(double)bb1[c]-mean*a1;
    a1s[c]=(float)a1;
    e1s[c]=(float)(a1*bc+d1);
  }
  __syncthreads();
  for(int idx=tid; idx<5280; idx+=256){
    int o=idx/264, r=idx-o*264, h=r/12, k=r-h*12;
    float s=0.f;
    for(int i=0;i<CIN_;i++) s += w2[(o*CIN_+i)*12+k]*a1s[i]*w1[i*CIN_+h];
    ws[OFF_WEFF+idx]=s;
  }
  if(tid<COUT_){
    float pre=0.f;
    ws[OFF_BPRE+tid*13+0]=0.f;
    for(int k=0;k<12;k++){
      float wb=0.f;
      for(int i=0;i<CIN_;i++) wb += w2[(tid*CIN_+i)*12+k]*e1s[i];
      pre += wb;
      ws[OFF_BPRE+tid*13+k+1]=pre;
    }
  }
}

// direct conv x->h2 + per-patch covariance + bn2 sums. ONE (b,p) PER BLOCK.
// R18-proven 13-chunk / 240-thread version.
__global__ __launch_bounds__(256) void k_cov(const float* __restrict__ x,
                                             float* __restrict__ ws){
  __shared__ float preL[260];
  __shared__ float xs[CIN_][168];
  __shared__ float h2w[COUT_][156];
  __shared__ float pmu[COUT_];
  int blk=blockIdx.x, tid=threadIdx.x;
  int b=blk/3, p=blk-3*b;
  const int off = (p==0)?0:((p==1)?147:293);
  const int L = (p==0)?147:146;
  for(int i=tid;i<260;i+=256) preL[i]=ws[OFF_BPRE+i];
  const float* xb = x + (size_t)b*CIN_*T1_;
  for(int idx=tid; idx<CIN_*168; idx+=256){
    int h=idx/168, c2=idx-h*168;
    int gxt = off-6+c2;
    xs[h][c2] = (c2<167 && gxt>=0 && gxt<T1_) ? xb[h*T1_+gxt] : 0.f;
  }
  __syncthreads();
  int o = tid/12, cch = tid-12*o;
  int t0 = cch*13;
  if(tid<240){
    float acc[13];
    #pragma unroll
    for(int j=0;j<13;j++){
      int gt = off+t0+j;
      int kmin = 6-gt; kmin = kmin<0?0:kmin;
      int kmax = 443-gt; kmax = kmax>11?11:kmax;
      acc[j] = (kmax>=kmin)? preL[o*13+kmax+1]-preL[o*13+kmin] : 0.f;
    }
    const float* Wo = ws + OFF_WEFF + o*264;   // global, L1-hot
    for(int h=0;h<CIN_;h++){
      float xw[24];
      #pragma unroll
      for(int c2=0;c2<24;c2++) xw[c2]=xs[h][t0+c2];
      const float* Wh = Wo + h*12;
      #pragma unroll
      for(int k=0;k<12;k++){
        float w=Wh[k];
        #pragma unroll
        for(int j=0;j<13;j++) acc[j] += w*xw[j+k];
      }
    }
    #pragma unroll
    for(int j=0;j<13;j++) if(t0+j<L) h2w[o][t0+j]=acc[j];
  } else {
    int npad = 156-L;
    for(int z=tid-240; z<COUT_*npad; z+=16){
      int oo=z/npad, c2=z-oo*npad;
      h2w[oo][L+c2]=0.f;
    }
  }
  __syncthreads();
  int pi=0,pj=0;
  if(tid<210){ int r=tid,i=0; while(true){int c=COUT_-i; if(r<c)break; r-=c; i++;} pi=i; pj=i+r; }
  int sc = tid-210;
  float s=0.f;
  if(tid<210){
    const float4* ri=(const float4*)&h2w[pi][0];
    const float4* rj=(const float4*)&h2w[pj][0];
    for(int t=0;t<39;t++){
      float4 a=ri[t], bb=rj[t];
      s += a.x*bb.x + a.y*bb.y + a.z*bb.z + a.w*bb.w;
    }
  } else if(sc>=0 && sc<COUT_){
    const float4* rc=(const float4*)&h2w[sc][0];
    float s1=0.f,s2=0.f;
    for(int t=0;t<39;t++){
      float4 a=rc[t];
      s1 += a.x+a.y+a.z+a.w;
      s2 += a.x*a.x+a.y*a.y+a.z*a.z+a.w*a.w;
    }
    pmu[sc]=s1/(float)L;
    atomicAdd(&ws[OFF_SUM2+sc], s1);
    atomicAdd(&ws[OFF_SSQ2+sc], s2);
  }
  __syncthreads();
  if(tid<210){
    s -= (float)L*pmu[pi]*pmu[pj];
    float* Cb = ws + OFF_C + (size_t)blk*400;
    Cb[pi*COUT_+pj]=s; Cb[pj*COUT_+pi]=s;
  }
}

// ---------------------------------------------------------------------------
// One-sided Jacobi, ONE COLUMN PER LANE (circle-method pairing, R11-verified).
// Exit 3e-2 (R17-verified; 1e-1 rejected: residual ~s^2*Δlog ≈ 0.1 > thresh).
// ---------------------------------------------------------------------------
__device__ __forceinline__ void bl_jacobi18(float own[18], float &dgo,
                                            int l18, int gb, bool act, int maxsweep){
  int self = gb + l18;
  for(int sweep=0; sweep<maxsweep; sweep++){
    { float d0=0.f,d1=0.f;
      #pragma unroll
      for(int k=0;k<18;k+=2){ d0+=own[k]*own[k]; d1+=own[k+1]*own[k+1]; }
      dgo=d0+d1;
    }
    float smax=0.f;
    for(int r=0;r<17;r++){
      int t = 2*r - l18;
      t += (t<0)?17:0;
      t -= (t>=17)?17:0;
      int pa = (l18==17)? r : ((t==l18)?17:t);
      int src = act ? (gb + pa) : self;
      float oth[18];
      #pragma unroll
      for(int k=0;k<18;k++) oth[k]=__shfl(own[k], src);
      float dgx = __shfl(dgo, src);
      float a0=0.f,a1=0.f;
      #pragma unroll
      for(int k=0;k<18;k+=2){ a0+=own[k]*oth[k]; a1+=own[k+1]*oth[k+1]; }
      float apq=a0+a1;
      bool isP = l18 < pa;
      float dgp = isP? dgo : dgx;
      float dgq = isP? dgx : dgo;
      float tau = __fdividef(dgq-dgp, 2.f*apq);
      float tt  = __fdividef(copysignf(1.f,tau), fabsf(tau)+sqrtf(1.f+tau*tau));
      float c   = rsqrtf(1.f+tt*tt);
      float s   = tt*c;
      bool  z   = (apq==0.f) || !act;
      tt=z?0.f:tt; c=z?1.f:c; s=z?0.f:s;
      smax=fmaxf(smax,fabsf(s));
      float sgn = isP ? -s : s;       // p: c*p - s*q ; q: s*p + c*q
      #pragma unroll
      for(int k=0;k<18;k++) own[k] = c*own[k] + sgn*oth[k];
      dgo = isP ? (dgp - tt*apq) : (dgq + tt*apq);
    }
    if(__all(smax<3e-2f)) break;
  }
  float d0=0.f,d1=0.f;
  #pragma unroll
  for(int k=0;k<18;k+=2){ d0+=own[k]*own[k]; d1+=own[k+1]*own[k+1]; }
  dgo=d0+d1;
}

// LDS float offsets for k_fused (S[6374] = ~25.5 KB)
#define F_A2S 0
#define F_WA 20
#define F_CS 1100
#define F_TT 2300
#define F_TRS 3434
#define F_LTR 3437
#define F_LG 3440
#define F_E9 6356
#define F_PROB 6365
// aliases (dead-region reuse):
#define F_SC 20        // Mc1: per-wave w at F_SC + w*1026 (3x342 each)
#define F_GL1 3098     // 3 x 54
#define F_ML 20        // 972 (after Mc1 dead)
#define F_MC2 992      // 3 x 342
#define F_GL2 2018     // 54
#define F_FEAT 3440    // 513 (aliases lg, dead after ml)

// Fused: per block (batch b): 3 waves, wave w = patch p.
// Congruence uses COLUMN-CACHED remap (R19-verified): phase a caches C[:,j]
// in regs, phase b caches W[:,c]. Phase 3 (eigh2) in wave 0 only.
__global__ __launch_bounds__(192) void k_fused(const float* __restrict__ Wq,
                                               const float* __restrict__ Wk,
                                               const float* __restrict__ Wv,
                                               const float* __restrict__ g2,
                                               const float* __restrict__ lw,
                                               const float* __restrict__ lb,
                                               float* __restrict__ ws,
                                               float* __restrict__ out){
  __shared__ float S[6374];
  int b=blockIdx.x, tid=threadIdx.x;
  int w=tid>>6, wl=tid&63;
  if(tid<20){
    const double N=(double)B_*T2_;
    double m=(double)ws[OFF_SUM2+tid]/N;
    double v=(double)ws[OFF_SSQ2+tid]/N - m*m;
    S[F_A2S+tid]=(float)((double)g2[tid]/sqrt(v+1e-5));
  }
  __syncthreads();
  // Wa = W * a2 (block-wide)
  for(int i=tid;i<1080;i+=192){
    int m=i/360, r=i-m*360, row=r/18;
    const float* W=(m==0)?Wq:((m==1)?Wk:Wv);
    S[F_WA+i]=W[r]*S[F_A2S+row];
  }
  // per-wave: stage this patch's C
  {
    const float* Cb=ws+OFF_C+((size_t)b*3+w)*400;
    for(int i=wl;i<400;i+=64) S[F_CS+w*400+i]=Cb[i];
  }
  // trace (lane 0 of each wave; in-wave DS order guarantees Cs visible)
  if(wl==0){
    float tr=0.f;
    #pragma unroll
    for(int i=0;i<20;i++) tr += S[F_CS+w*400+i*20+i]*S[F_A2S+i]*S[F_A2S+i];
    S[F_TRS+w]=tr;
    S[F_LTR+w]=logf(tr);
  }
  __syncthreads();
  // 3 congruences per wave: B_m = Wa_m^T C_w Wa_m -> lg[m][w]
  // phase a: lane j=wl%20 fixed -> cache C[:,j]; outputs a = wl/20 + 3s
  {
    const float* Cw=S+F_CS+w*400;
    float creg[20];
    int j = wl%20, ab = wl/20;   // ab in 0..2 for wl<60
    if(wl<60){
      #pragma unroll
      for(int i=0;i<20;i++) creg[i]=Cw[i*20+j];
    }
    for(int m=0;m<3;m++){
      const float* Wm=S+F_WA+m*360;
      float* Tw=S+F_TT+w*378;
      if(wl<60){
        #pragma unroll
        for(int s6=0;s6<6;s6++){
          int a = ab + 3*s6;
          float t=0.f;
          #pragma unroll
          for(int i=0;i<20;i++) t += Wm[i*18+a]*creg[i];
          Tw[a*21+j]=t;
        }
      }
      __syncthreads();
      // phase b: lane c=wl%18 fixed -> cache Wm[:,c]; outputs a = wl/18 + 3s
      {
        int c = wl%18, ab2 = wl/18;   // ab2 in 0..2 for wl<54
        if(wl<54){
          float wreg[20];
          #pragma unroll
          for(int jj=0;jj<20;jj++) wreg[jj]=Wm[jj*18+c];
          #pragma unroll
          for(int s6=0;s6<6;s6++){
            int a = ab2 + 3*s6;
            float t=0.f;
            #pragma unroll
            for(int jj=0;jj<20;jj++) t += Tw[a*21+jj]*wreg[jj];
            S[F_LG + m*972 + w*324 + a*18 + c]=t;
          }
        }
      }
      __syncthreads();
    }
  }
  int g=wl/18, l18=wl-18*g;
  bool act=(g<3);
  float tr_w=S[F_TRS+w], ltr_w=S[F_LTR+w];
  float sh=1e-5f*tr_w;
  float own[18], dgo=0.f;
  if(act){
    const float* Ag=S+F_LG+g*972+w*324;
    #pragma unroll
    for(int k=0;k<18;k++)
      own[k]=0.5f*(Ag[k*18+l18]+Ag[l18*18+k]) + ((k==l18)?sh:0.f);
  } else {
    #pragma unroll
    for(int k=0;k<18;k++) own[k]=0.f;
  }
  __syncthreads();   // all reads of Wa/Cs/Tt/lg-B done; Mc1 may alias
  bl_jacobi18(own,dgo,l18,g*18,act,8);
  // spectral weight: lambda_true=sqrt(dg)/tr; gv=(0.5*log(dg)-log(tr))/dg
  float dp=fmaxf(dgo,1e-30f);
  float gv=__fdividef(0.5f*logf(dp)-ltr_w, dp);
  float* Mc1=S+F_SC+w*1026;
  float* gl1=S+F_GL1+w*54;
  if(act){
    #pragma unroll
    for(int k=0;k<18;k++) Mc1[g*342 + k*19 + l18]=own[k];
    gl1[g*18+l18]=gv;
  }
  // logm rows -> lg[mat][w] (in-wave: DS in-order after Mc1 writes)
  if(wl<54){
    int mat=g, i=l18;
    float w18[18];
    #pragma unroll
    for(int k=0;k<18;k++) w18[k]=gl1[mat*18+k]*Mc1[mat*342+i*19+k];
    float* ob=S+F_LG+mat*972+w*324+i*18;
    for(int j=0;j<18;j++){
      float s=0.f;
      #pragma unroll
      for(int k=0;k<18;k++) s += w18[k]*Mc1[mat*342+j*19+k];
      ob[j]=s;
    }
  }
  __syncthreads();   // lg (logQ|logK|logV) complete
  // energies (wave 0, 36 lanes: 9 dots x 4-lane split)
  if(tid<36){
    int d=tid>>2, sub=tid&3;
    int ii=d/3, p=d-ii*3;
    const float* kk=S+F_LG+972+ii*324+sub*81;
    const float* qq=S+F_LG+p*324+sub*81;
    float s=0.f;
    for(int el=0;el<81;el++){ float dd=kk[el]-qq[el]; s+=dd*dd; }
    s += __shfl_xor(s,1); s += __shfl_xor(s,2);
    if(sub==0) S[F_E9+d]=s;
  }
  __syncthreads();
  if(tid<3){
    int p=tid;
    float f0=1.f/(1.f+log1pf(S[F_E9+0+p]));
    float f1=1.f/(1.f+log1pf(S[F_E9+3+p]));
    float f2=1.f/(1.f+log1pf(S[F_E9+6+p]));
    float mx=fmaxf(f0,fmaxf(f1,f2));
    float x0=expf(f0-mx), x1=expf(f1-mx), x2=expf(f2-mx);
    float inv=1.f/(x0+x1+x2);
    S[F_PROB+p*3+0]=x0*inv; S[F_PROB+p*3+1]=x1*inv; S[F_PROB+p*3+2]=x2*inv;
  }
  __syncthreads();
  // ml = sum_i prob * logV  (Mc1 dead -> F_ML aliases it)
  for(int idx=tid; idx<972; idx+=192){
    int p=idx/324, el=idx-p*324;
    const float* LV=S+F_LG+1944;
    S[F_ML+idx]=S[F_PROB+p*3+0]*LV[el]+S[F_PROB+p*3+1]*LV[324+el]+S[F_PROB+p*3+2]*LV[648+el];
  }
  __syncthreads();
  // eigh2: WAVE 0 ONLY — 54 lanes handle all 3 ml matrices (+12I shift).
  if(w==0){
    int g2i=wl/18, l2=wl-18*g2i;
    bool act2=(g2i<3);
    float own2[18], dgo2=0.f;
    if(act2){
      const float* Ag=S+F_ML+g2i*324;
      #pragma unroll
      for(int k=0;k<18;k++)
        own2[k]=0.5f*(Ag[k*18+l2]+Ag[l2*18+k]) + ((k==l2)?12.f:0.f);
    } else {
      #pragma unroll
      for(int k=0;k<18;k++) own2[k]=0.f;
    }
    bl_jacobi18(own2,dgo2,l2,g2i*18,act2,8);
    float lam=sqrtf(fmaxf(dgo2,1e-12f));
    float gv2=__fdividef(fmaxf(lam-12.f,-9.2103404f), fmaxf(dgo2,1e-12f));
    if(act2){
      #pragma unroll
      for(int k=0;k<18;k++) S[F_MC2 + g2i*342 + k*19 + l2]=own2[k];
      S[F_GL2 + g2i*18 + l2]=gv2;
    }
  }
  __syncthreads();   // all Mc2/gl2 ready
  // triu(tang) -> feat (aliases lg region, dead)
  if(tid<54){
    int mat=tid/18, i=tid-mat*18;
    float w18[18];
    #pragma unroll
    for(int k=0;k<18;k++) w18[k]=S[F_GL2+mat*18+k]*S[F_MC2+mat*342+i*19+k];
    int base = mat*171 + (i*18 - (i*(i-1))/2) - i;
    for(int j=i;j<18;j++){
      float s=0.f;
      #pragma unroll
      for(int k=0;k<18;k++) s += w18[k]*S[F_MC2+mat*342+j*19+k];
      S[F_FEAT+base+j]=s;
    }
  }
  __syncthreads();
  // linear (wave 0): out[b][j] = lb[j] + dot(feat, lw[j])
  if(tid<64){
    int j4 = tid&3, chunk = tid>>2;
    float s=0.f;
    const float* wj = lw + j4*513;
    for(int k=chunk; k<513; k+=16) s += S[F_FEAT+k]*wj[k];
    s += __shfl_xor(s,4); s += __shfl_xor(s,8);
    s += __shfl_xor(s,16); s += __shfl_xor(s,32);
    if(chunk==0) out[b*4+j4] = s + lb[j4];
  }
}

extern "C" void kernel_launch(void* const* d_in, const int* in_sizes, int n_in,
                              void* d_out, int out_size, void* d_ws, size_t ws_size,
                              hipStream_t stream){
  const float* x  =(const float*)d_in[0];
  const float* w1 =(const float*)d_in[1];
  const float* cb1=(const float*)d_in[2];
  const float* g1 =(const float*)d_in[3];
  const float* bb1=(const float*)d_in[4];
  const float* w2 =(const float*)d_in[5];
  // d_in[6] conv2_b, d_in[8] bn2_b: provably cancel
  const float* g2 =(const float*)d_in[7];
  const float* Wq =(const float*)d_in[9];
  const float* Wk =(const float*)d_in[10];
  const float* Wv =(const float*)d_in[11];
  const float* lw =(const float*)d_in[12];
  const float* lb =(const float*)d_in[13];
  float* ws=(float*)d_ws;
  float* out=(float*)d_out;

  k_zero<<<1,256,0,stream>>>(ws);
  k_moment<<<B_,256,0,stream>>>(x,ws);
  k_prep<<<1,256,0,stream>>>(w1,cb1,g1,bb1,w2,ws);
  k_cov<<<3072,256,0,stream>>>(x,ws);            // one (b,p) per block
  k_fused<<<B_,192,0,stream>>>(Wq,Wk,Wv,g2,lw,lb,ws,out);  // fin2+eigh3+att+eigh2+feat+linear
}

// Round 22
// 368.782 us; speedup vs baseline: 1.1888x; 1.0220x over previous
//
#include <hip/hip_runtime.h>
#include <cmath>

#define B_ 1024
#define CIN_ 22
#define T1_ 438
#define COUT_ 20
#define T2_ 439

// ws float offsets
#define OFF_S 0
#define OFF_M 32
#define OFF_SUM2 576
#define OFF_SSQ2 608
#define OFF_A2 640
#define OFF_ACC_END 704
#define OFF_C 1024
#define OFF_WEFF (OFF_C + B_*3*400)
#define OFF_BPRE (OFF_WEFF + 5280)

__global__ __launch_bounds__(256) void k_zero(float* ws){
  for(int i=threadIdx.x; i<OFF_ACC_END; i+=256) ws[i]=0.f;
}

// bn1 stats via second-moment matrix of x: S[22], M[22][22] (triu), float4 dots.
__global__ __launch_bounds__(256) void k_moment(const float* __restrict__ x, float* __restrict__ ws){
  __shared__ float xs[CIN_][444];
  int b=blockIdx.x, tid=threadIdx.x;
  const float* xb = x + (size_t)b*CIN_*T1_;
  const float4* xb4 = (const float4*)xb;
  for(int i4=tid; i4<2409; i4+=256){
    float4 v = xb4[i4];
    int e = i4<<2;
    int h0=e/T1_,     t0=e-h0*T1_;
    int h1=(e+1)/T1_, t1=(e+1)-h1*T1_;
    int h2=(e+2)/T1_, t2=(e+2)-h2*T1_;
    int h3=(e+3)/T1_, t3=(e+3)-h3*T1_;
    xs[h0][t0]=v.x; xs[h1][t1]=v.y; xs[h2][t2]=v.z; xs[h3][t3]=v.w;
  }
  if(tid<CIN_){
    #pragma unroll
    for(int t=T1_;t<444;t++) xs[tid][t]=0.f;
  }
  __syncthreads();
  for(int tgt=tid; tgt<275; tgt+=256){
    if(tgt<253){
      int r=tgt, i=0;
      while(true){ int c=CIN_-i; if(r<c) break; r-=c; i++; }
      int j=i+r;
      const float4* ri=(const float4*)&xs[i][0];
      const float4* rj=(const float4*)&xs[j][0];
      float acc=0.f;
      for(int t=0;t<111;t++){
        float4 a=ri[t], bb=rj[t];
        acc += a.x*bb.x + a.y*bb.y + a.z*bb.z + a.w*bb.w;
      }
      atomicAdd(&ws[OFF_M + i*CIN_ + j], acc);
    } else {
      int c=tgt-253;
      const float4* rc=(const float4*)&xs[c][0];
      float acc=0.f;
      for(int t=0;t<111;t++){
        float4 a=rc[t];
        acc += a.x + a.y + a.z + a.w;
      }
      atomicAdd(&ws[OFF_S + c], acc);
    }
  }
}

// bn1 closed-form + fold conv1/bn1 into conv2: Weff[o][h][k], bias prefix pre[o][13]
__global__ __launch_bounds__(256) void k_prep(const float* __restrict__ w1, const float* __restrict__ cb1,
                                              const float* __restrict__ g1, const float* __restrict__ bb1,
                                              const float* __restrict__ w2, float* __restrict__ ws){
  __shared__ float a1s[CIN_], e1s[CIN_];
  int tid=threadIdx.x;
  if(tid<CIN_){
    int c=tid;
    const double N = (double)B_*T1_;
    double wS=0.0, wMw=0.0;
    for(int h=0;h<CIN_;h++) wS += (double)w1[c*CIN_+h]*(double)ws[OFF_S+h];
    for(int h=0;h<CIN_;h++){
      for(int h2=0;h2<CIN_;h2++){
        int i=h<h2?h:h2, j=h<h2?h2:h;
        wMw += (double)w1[c*CIN_+h]*(double)w1[c*CIN_+h2]*(double)ws[OFF_M+i*CIN_+j];
      }
    }
    double bc=cb1[c];
    double mean=wS/N+bc;
    double ex2=(wMw+2.0*bc*wS)/N+bc*bc;
    double var=ex2-mean*mean;
    double a1=(double)g1[c]/sqrt(var+1e-5);
    double d1=(double)bb1[c]-mean*a1;
    a1s[c]=(float)a1;
    e1s[c]=(float)(a1*bc+d1);
  }
  __syncthreads();
  for(int idx=tid; idx<5280; idx+=256){
    int o=idx/264, r=idx-o*264, h=r/12, k=r-h*12;
    float s=0.f;
    for(int i=0;i<CIN_;i++) s += w2[(o*CIN_+i)*12+k]*a1s[i]*w1[i*CIN_+h];
    ws[OFF_WEFF+idx]=s;
  }
  if(tid<COUT_){
    float pre=0.f;
    ws[OFF_BPRE+tid*13+0]=0.f;
    for(int k=0;k<12;k++){
      float wb=0.f;
      for(int i=0;i<CIN_;i++) wb += w2[(tid*CIN_+i)*12+k]*e1s[i];
      pre += wb;
      ws[OFF_BPRE+tid*13+k+1]=pre;
    }
  }
}

// direct conv x->h2 + per-patch covariance + bn2 sums. ONE (b,p) PER BLOCK.
// R18-proven 13-chunk / 240-thread version.
__global__ __launch_bounds__(256) void k_cov(const float* __restrict__ x,
                                             float* __restrict__ ws){
  __shared__ float preL[260];
  __shared__ float xs[CIN_][168];
  __shared__ float h2w[COUT_][156];
  __shared__ float pmu[COUT_];
  int blk=blockIdx.x, tid=threadIdx.x;
  int b=blk/3, p=blk-3*b;
  const int off = (p==0)?0:((p==1)?147:293);
  const int L = (p==0)?147:146;
  for(int i=tid;i<260;i+=256) preL[i]=ws[OFF_BPRE+i];
  const float* xb = x + (size_t)b*CIN_*T1_;
  for(int idx=tid; idx<CIN_*168; idx+=256){
    int h=idx/168, c2=idx-h*168;
    int gxt = off-6+c2;
    xs[h][c2] = (c2<167 && gxt>=0 && gxt<T1_) ? xb[h*T1_+gxt] : 0.f;
  }
  __syncthreads();
  int o = tid/12, cch = tid-12*o;
  int t0 = cch*13;
  if(tid<240){
    float acc[13];
    #pragma unroll
    for(int j=0;j<13;j++){
      int gt = off+t0+j;
      int kmin = 6-gt; kmin = kmin<0?0:kmin;
      int kmax = 443-gt; kmax = kmax>11?11:kmax;
      acc[j] = (kmax>=kmin)? preL[o*13+kmax+1]-preL[o*13+kmin] : 0.f;
    }
    const float* Wo = ws + OFF_WEFF + o*264;   // global, L1-hot
    for(int h=0;h<CIN_;h++){
      float xw[24];
      #pragma unroll
      for(int c2=0;c2<24;c2++) xw[c2]=xs[h][t0+c2];
      const float* Wh = Wo + h*12;
      #pragma unroll
      for(int k=0;k<12;k++){
        float w=Wh[k];
        #pragma unroll
        for(int j=0;j<13;j++) acc[j] += w*xw[j+k];
      }
    }
    #pragma unroll
    for(int j=0;j<13;j++) if(t0+j<L) h2w[o][t0+j]=acc[j];
  } else {
    int npad = 156-L;
    for(int z=tid-240; z<COUT_*npad; z+=16){
      int oo=z/npad, c2=z-oo*npad;
      h2w[oo][L+c2]=0.f;
    }
  }
  __syncthreads();
  int pi=0,pj=0;
  if(tid<210){ int r=tid,i=0; while(true){int c=COUT_-i; if(r<c)break; r-=c; i++;} pi=i; pj=i+r; }
  int sc = tid-210;
  float s=0.f;
  if(tid<210){
    const float4* ri=(const float4*)&h2w[pi][0];
    const float4* rj=(const float4*)&h2w[pj][0];
    for(int t=0;t<39;t++){
      float4 a=ri[t], bb=rj[t];
      s += a.x*bb.x + a.y*bb.y + a.z*bb.z + a.w*bb.w;
    }
  } else if(sc>=0 && sc<COUT_){
    const float4* rc=(const float4*)&h2w[sc][0];
    float s1=0.f,s2=0.f;
    for(int t=0;t<39;t++){
      float4 a=rc[t];
      s1 += a.x+a.y+a.z+a.w;
      s2 += a.x*a.x+a.y*a.y+a.z*a.z+a.w*a.w;
    }
    pmu[sc]=s1/(float)L;
    atomicAdd(&ws[OFF_SUM2+sc], s1);
    atomicAdd(&ws[OFF_SSQ2+sc], s2);
  }
  __syncthreads();
  if(tid<210){
    s -= (float)L*pmu[pi]*pmu[pj];
    float* Cb = ws + OFF_C + (size_t)blk*400;
    Cb[pi*COUT_+pj]=s; Cb[pj*COUT_+pi]=s;
  }
}

// ---------------------------------------------------------------------------
// One-sided Jacobi, ONE COLUMN PER LANE (circle-method pairing, R11-verified).
// Exit 3e-2 (R17-verified). Pairing computed INCREMENTALLY: t_{r+1}=t_r+2 mod 17.
// ---------------------------------------------------------------------------
__device__ __forceinline__ void bl_jacobi18(float own[18], float &dgo,
                                            int l18, int gb, bool act, int maxsweep){
  int self = gb + l18;
  const int t0v = (17 - (l18 % 17)) % 17;   // t at r=0 (unused for l18==17)
  for(int sweep=0; sweep<maxsweep; sweep++){
    { float d0=0.f,d1=0.f;
      #pragma unroll
      for(int k=0;k<18;k+=2){ d0+=own[k]*own[k]; d1+=own[k+1]*own[k+1]; }
      dgo=d0+d1;
    }
    float smax=0.f;
    int t = t0v;
    for(int r=0;r<17;r++){
      int pa = (l18==17)? r : ((t==l18)?17:t);
      int src = act ? (gb + pa) : self;
      float oth[18];
      #pragma unroll
      for(int k=0;k<18;k++) oth[k]=__shfl(own[k], src);
      float dgx = __shfl(dgo, src);
      float a0=0.f,a1=0.f;
      #pragma unroll
      for(int k=0;k<18;k+=2){ a0+=own[k]*oth[k]; a1+=own[k+1]*oth[k+1]; }
      float apq=a0+a1;
      bool isP = l18 < pa;
      float dgp = isP? dgo : dgx;
      float dgq = isP? dgx : dgo;
      float tau = __fdividef(dgq-dgp, 2.f*apq);
      float tt  = __fdividef(copysignf(1.f,tau), fabsf(tau)+sqrtf(1.f+tau*tau));
      float c   = rsqrtf(1.f+tt*tt);
      float s   = tt*c;
      bool  z   = (apq==0.f) || !act;
      tt=z?0.f:tt; c=z?1.f:c; s=z?0.f:s;
      smax=fmaxf(smax,fabsf(s));
      float sgn = isP ? -s : s;       // p: c*p - s*q ; q: s*p + c*q
      #pragma unroll
      for(int k=0;k<18;k++) own[k] = c*own[k] + sgn*oth[k];
      dgo = isP ? (dgp - tt*apq) : (dgq + tt*apq);
      t += 2; t -= (t>=17)?17:0;
    }
    if(__all(smax<3e-2f)) break;
  }
  float d0=0.f,d1=0.f;
  #pragma unroll
  for(int k=0;k<18;k+=2){ d0+=own[k]*own[k]; d1+=own[k+1]*own[k+1]; }
  dgo=d0+d1;
}

// LDS float offsets for k_fused (S[6374] = ~25.5 KB)
#define F_A2S 0
#define F_WA 20
#define F_CS 1100
#define F_TT 2300
#define F_TRS 3434
#define F_LTR 3437
#define F_LG 3440
#define F_E9 6356
#define F_PROB 6365
// aliases (dead-region reuse):
#define F_SC 20        // Mc1: per-wave w at F_SC + w*1026 (3x342 each)
#define F_GL1 3098     // 3 x 54
#define F_ML 20        // 972 (after Mc1 dead)
#define F_MC2 992      // 3 x 342
#define F_GL2 2018     // 54
#define F_FEAT 3440    // 513 (aliases lg, dead after ml)

// Fused: per block (batch b): 3 waves, wave w = patch p.
// BARRIER AUDIT (this round): only 5 block barriers have true cross-wave deps
// (a2s->Wa, Wa->congruence, lg->energies, prob->ml, ml->eigh2). All intra-wave
// LDS orderings (Tw phases, E9->softmax, Mc2->feat->linear) use
// __builtin_amdgcn_wave_barrier() — in-wave DS ops are in-order (the Mc1->logm
// path has relied on this since R12); the fence only blocks compiler reorder.
__global__ __launch_bounds__(192) void k_fused(const float* __restrict__ Wq,
                                               const float* __restrict__ Wk,
                                               const float* __restrict__ Wv,
                                               const float* __restrict__ g2,
                                               const float* __restrict__ lw,
                                               const float* __restrict__ lb,
                                               float* __restrict__ ws,
                                               float* __restrict__ out){
  __shared__ float S[6374];
  int b=blockIdx.x, tid=threadIdx.x;
  int w=tid>>6, wl=tid&63;
  if(tid<20){
    const double N=(double)B_*T2_;
    double m=(double)ws[OFF_SUM2+tid]/N;
    double v=(double)ws[OFF_SSQ2+tid]/N - m*m;
    S[F_A2S+tid]=(float)((double)g2[tid]/sqrt(v+1e-5));
  }
  __syncthreads();                       // a2s -> Wa (cross-wave)
  // Wa = W * a2 (block-wide, float4 loads+stores; 360%4==0 so m uniform per vec)
  for(int i4=tid;i4<270;i4+=192){
    int e=i4<<2;
    int m=e/360, r=e-m*360;
    const float* W=(m==0)?Wq:((m==1)?Wk:Wv);
    float4 wv=*(const float4*)(W+r);
    float4 o;
    o.x=wv.x*S[F_A2S+(r  )/18];
    o.y=wv.y*S[F_A2S+(r+1)/18];
    o.z=wv.z*S[F_A2S+(r+2)/18];
    o.w=wv.w*S[F_A2S+(r+3)/18];
    *(float4*)(S+F_WA+e)=o;
  }
  // per-wave: stage this patch's C (float4)
  {
    const float4* Cb4=(const float4*)(ws+OFF_C+((size_t)b*3+w)*400);
    float4* Cs4=(float4*)(S+F_CS+w*400);
    for(int i4=wl;i4<100;i4+=64) Cs4[i4]=Cb4[i4];
  }
  // trace (lane 0 of each wave; in-wave DS order guarantees Cs visible)
  if(wl==0){
    float tr=0.f;
    #pragma unroll
    for(int i=0;i<20;i++) tr += S[F_CS+w*400+i*20+i]*S[F_A2S+i]*S[F_A2S+i];
    S[F_TRS+w]=tr;
    S[F_LTR+w]=logf(tr);
  }
  __syncthreads();                       // Wa complete (cross-wave)
  // 3 congruences per wave: B_m = Wa_m^T C_w Wa_m -> lg[m][w]
  // phase a caches C[:,j]; phase b caches W[:,c]. Per-wave buffers -> wave fences.
  {
    const float* Cw=S+F_CS+w*400;
    float creg[20];
    int j = wl%20, ab = wl/20;   // ab in 0..2 for wl<60
    int c = wl%18, ab2 = wl/18;  // ab2 in 0..2 for wl<54
    if(wl<60){
      #pragma unroll
      for(int i=0;i<20;i++) creg[i]=Cw[i*20+j];
    }
    for(int m=0;m<3;m++){
      const float* Wm=S+F_WA+m*360;
      float* Tw=S+F_TT+w*378;
      if(wl<60){
        #pragma unroll
        for(int s6=0;s6<6;s6++){
          int a = ab + 3*s6;
          float t=0.f;
          #pragma unroll
          for(int i=0;i<20;i++) t += Wm[i*18+a]*creg[i];
          Tw[a*21+j]=t;
        }
      }
      __builtin_amdgcn_wave_barrier();
      if(wl<54){
        float wreg[20];
        #pragma unroll
        for(int jj=0;jj<20;jj++) wreg[jj]=Wm[jj*18+c];
        #pragma unroll
        for(int s6=0;s6<6;s6++){
          int a = ab2 + 3*s6;
          float t=0.f;
          #pragma unroll
          for(int jj=0;jj<20;jj++) t += Tw[a*21+jj]*wreg[jj];
          S[F_LG + m*972 + w*324 + a*18 + c]=t;
        }
      }
      __builtin_amdgcn_wave_barrier();
    }
  }
  int g=wl/18, l18=wl-18*g;
  bool act=(g<3);
  float tr_w=S[F_TRS+w], ltr_w=S[F_LTR+w];
  float sh=1e-5f*tr_w;
  float own[18], dgo=0.f;
  if(act){
    const float* Ag=S+F_LG+g*972+w*324;
    #pragma unroll
    for(int k=0;k<18;k++)
      own[k]=0.5f*(Ag[k*18+l18]+Ag[l18*18+k]) + ((k==l18)?sh:0.f);
  } else {
    #pragma unroll
    for(int k=0;k<18;k++) own[k]=0.f;
  }
  __syncthreads();   // all reads of Wa/Cs/Tt done block-wide; Mc1 may alias
  bl_jacobi18(own,dgo,l18,g*18,act,8);
  // spectral weight: lambda_true=sqrt(dg)/tr; gv=(0.5*log(dg)-log(tr))/dg
  float dp=fmaxf(dgo,1e-30f);
  float gv=__fdividef(0.5f*logf(dp)-ltr_w, dp);
  float* Mc1=S+F_SC+w*1026;
  float* gl1=S+F_GL1+w*54;
  if(act){
    #pragma unroll
    for(int k=0;k<18;k++) Mc1[g*342 + k*19 + l18]=own[k];
    gl1[g*18+l18]=gv;
  }
  __builtin_amdgcn_wave_barrier();
  // logm rows -> lg[mat][w] (in-wave: DS in-order after Mc1 writes)
  if(wl<54){
    int mat=g, i=l18;
    float w18[18];
    #pragma unroll
    for(int k=0;k<18;k++) w18[k]=gl1[mat*18+k]*Mc1[mat*342+i*19+k];
    float* ob=S+F_LG+mat*972+w*324+i*18;
    for(int j=0;j<18;j++){
      float s=0.f;
      #pragma unroll
      for(int k=0;k<18;k++) s += w18[k]*Mc1[mat*342+j*19+k];
      ob[j]=s;
    }
  }
  __syncthreads();   // lg (logQ|logK|logV) complete (cross-wave)
  // energies (wave 0, 36 lanes: 9 dots x 4-lane split)
  if(tid<36){
    int d=tid>>2, sub=tid&3;
    int ii=d/3, p=d-ii*3;
    const float* kk=S+F_LG+972+ii*324+sub*81;
    const float* qq=S+F_LG+p*324+sub*81;
    float s=0.f;
    for(int el=0;el<81;el++){ float dd=kk[el]-qq[el]; s+=dd*dd; }
    s += __shfl_xor(s,1); s += __shfl_xor(s,2);
    if(sub==0) S[F_E9+d]=s;
  }
  __builtin_amdgcn_wave_barrier();
  if(tid<3){
    int p=tid;
    float f0=1.f/(1.f+log1pf(S[F_E9+0+p]));
    float f1=1.f/(1.f+log1pf(S[F_E9+3+p]));
    float f2=1.f/(1.f+log1pf(S[F_E9+6+p]));
    float mx=fmaxf(f0,fmaxf(f1,f2));
    float x0=expf(f0-mx), x1=expf(f1-mx), x2=expf(f2-mx);
    float inv=1.f/(x0+x1+x2);
    S[F_PROB+p*3+0]=x0*inv; S[F_PROB+p*3+1]=x1*inv; S[F_PROB+p*3+2]=x2*inv;
  }
  __syncthreads();   // prob -> ml (cross-wave)
  // ml = sum_i prob * logV  (Mc1 dead -> F_ML aliases it)
  for(int idx=tid; idx<972; idx+=192){
    int p=idx/324, el=idx-p*324;
    const float* LV=S+F_LG+1944;
    S[F_ML+idx]=S[F_PROB+p*3+0]*LV[el]+S[F_PROB+p*3+1]*LV[324+el]+S[F_PROB+p*3+2]*LV[648+el];
  }
  __syncthreads();   // ml -> eigh2 (cross-wave)
  // eigh2: WAVE 0 ONLY — 54 lanes handle all 3 ml matrices (+12I shift).
  if(w==0){
    int g2i=wl/18, l2=wl-18*g2i;
    bool act2=(g2i<3);
    float own2[18], dgo2=0.f;
    if(act2){
      const float* Ag=S+F_ML+g2i*324;
      #pragma unroll
      for(int k=0;k<18;k++)
        own2[k]=0.5f*(Ag[k*18+l2]+Ag[l2*18+k]) + ((k==l2)?12.f:0.f);
    } else {
      #pragma unroll
      for(int k=0;k<18;k++) own2[k]=0.f;
    }
    bl_jacobi18(own2,dgo2,l2,g2i*18,act2,8);
    float lam=sqrtf(fmaxf(dgo2,1e-12f));
    float gv2=__fdividef(fmaxf(lam-12.f,-9.2103404f), fmaxf(dgo2,1e-12f));
    if(act2){
      #pragma unroll
      for(int k=0;k<18;k++) S[F_MC2 + g2i*342 + k*19 + l2]=own2[k];
      S[F_GL2 + g2i*18 + l2]=gv2;
    }
  }
  __builtin_amdgcn_wave_barrier();
  // triu(tang) -> feat (aliases lg region, dead; wave-0 internal)
  if(tid<54){
    int mat=tid/18, i=tid-mat*18;
    float w18[18];
    #pragma unroll
    for(int k=0;k<18;k++) w18[k]=S[F_GL2+mat*18+k]*S[F_MC2+mat*342+i*19+k];
    int base = mat*171 + (i*18 - (i*(i-1))/2) - i;
    for(int j=i;j<18;j++){
      float s=0.f;
      #pragma unroll
      for(int k=0;k<18;k++) s += w18[k]*S[F_MC2+mat*342+j*19+k];
      S[F_FEAT+base+j]=s;
    }
  }
  __builtin_amdgcn_wave_barrier();
  // linear (wave 0): out[b][j] = lb[j] + dot(feat, lw[j])
  if(tid<64){
    int j4 = tid&3, chunk = tid>>2;
    float s=0.f;
    const float* wj = lw + j4*513;
    for(int k=chunk; k<513; k+=16) s += S[F_FEAT+k]*wj[k];
    s += __shfl_xor(s,4); s += __shfl_xor(s,8);
    s += __shfl_xor(s,16); s += __shfl_xor(s,32);
    if(chunk==0) out[b*4+j4] = s + lb[j4];
  }
}

extern "C" void kernel_launch(void* const* d_in, const int* in_sizes, int n_in,
                              void* d_out, int out_size, void* d_ws, size_t ws_size,
                              hipStream_t stream){
  const float* x  =(const float*)d_in[0];
  const float* w1 =(const float*)d_in[1];
  const float* cb1=(const float*)d_in[2];
  const float* g1 =(const float*)d_in[3];
  const float* bb1=(const float*)d_in[4];
  const float* w2 =(const float*)d_in[5];
  // d_in[6] conv2_b, d_in[8] bn2_b: provably cancel
  const float* g2 =(const float*)d_in[7];
  const float* Wq =(const float*)d_in[9];
  const float* Wk =(const float*)d_in[10];
  const float* Wv =(const float*)d_in[11];
  const float* lw =(const float*)d_in[12];
  const float* lb =(const float*)d_in[13];
  float* ws=(float*)d_ws;
  float* out=(float*)d_out;

  k_zero<<<1,256,0,stream>>>(ws);
  k_moment<<<B_,256,0,stream>>>(x,ws);
  k_prep<<<1,256,0,stream>>>(w1,cb1,g1,bb1,w2,ws);
  k_cov<<<3072,256,0,stream>>>(x,ws);            // one (b,p) per block
  k_fused<<<B_,192,0,stream>>>(Wq,Wk,Wv,g2,lw,lb,ws,out);  // fin2+eigh3+att+eigh2+feat+linear
}